// Round 1
// 461.967 us; speedup vs baseline: 1.1090x; 1.1090x over previous
//
#include <hip/hip_runtime.h>

#define H   512
#define W   512
#define HP  256   // row pairs (output height per quadrant)
#define WP  256   // output columns per quadrant
#define JSEG 32   // row-pairs per segment (32 -> 2048 blocks -> 8 blocks/CU)
#define SEGS (HP / JSEG)   // 8
#define IMGS 256  // 8*32

#define AS1 __attribute__((address_space(1)))
#define AS3 __attribute__((address_space(3)))

// async global->LDS: 16 B per lane; LDS dest = wave-uniform base + lane*16
__device__ __forceinline__ void g2lds16(const float* g, float* l) {
    __builtin_amdgcn_global_load_lds((const AS1 void*)g, (AS3 void*)l, 16, 0, 0);
}

// d_row[k] = p[2k+1] - 0.5*(p[2*em(k-1)] + p[2*em(k+1)]), em(-1)=1, em(256)=254
__device__ __forceinline__ float dr_scalar(const float* p, int k) {
    int a  = (k == 0)   ? 2   : (2 * k - 2);
    int b2 = (k == 255) ? 508 : (2 * k + 2);
    return p[2 * k + 1] - 0.5f * (p[a] + p[b2]);
}

// Row transform at column c of a 512-float row (now LDS-resident)
__device__ __forceinline__ void row_lift(const float* p, int c, bool mainPath,
                                         float& s, float& d) {
    if (mainPath) {  // c in [2,253]
        float2 vm2 = *(const float2*)(p + 2 * c - 4);
        float2 vm1 = *(const float2*)(p + 2 * c - 2);
        float2 v0  = *(const float2*)(p + 2 * c);
        float2 vp1 = *(const float2*)(p + 2 * c + 2);
        float2 vp2 = *(const float2*)(p + 2 * c + 4);
        float dm = vm1.y - 0.5f * (vm2.x + v0.x);   // d[c-1]
        float d0 = v0.y  - 0.5f * (vm1.x + vp1.x);  // d[c]
        float dp = vp1.y - 0.5f * (v0.x  + vp2.x);  // d[c+1]
        s = v0.x + 0.25f * (dm + dp);
        d = d0;
    } else {         // c in {0,1,254,255}: reflect-mapped indices
        int cm = (c == 0)   ? 1   : c - 1;
        int cp = (c == 255) ? 254 : c + 1;
        float dm = dr_scalar(p, cm);
        float d0 = dr_scalar(p, c);
        float dp = dr_scalar(p, cp);
        s = p[2 * c] + 0.25f * (dm + dp);
        d = d0;
    }
}

__global__ __launch_bounds__(256, 8)
void lwt53_2d_fused(const float* __restrict__ x, float* __restrict__ out) {
    // double-buffered row pair: rows 2j and 2j+1 contiguous (4 KiB each buffer)
    __shared__ float buf[2][2 * W];

    const int tid = threadIdx.x;
    const int c   = tid;                    // output column 0..255
    const int img = blockIdx.x / SEGS;      // 0..255 (= b*32 + ch)
    const int seg = blockIdx.x % SEGS;
    const int j0  = seg * JSEG;

    const float* ib = x + (size_t)img * (H * W);
    const int b  = img >> 5;
    const int ch = img & 31;
    // out[((b*128 + q*32 + ch)*256 + row)*256 + col], q: 0=LL 1=LH 2=HL 3=HH
    float* const outLL = out + (((size_t)b * 128 +  0 + ch) << 16) + c;
    float* const outLH = out + (((size_t)b * 128 + 32 + ch) << 16) + c;
    float* const outHL = out + (((size_t)b * 128 + 64 + ch) << 16) + c;
    float* const outHH = out + (((size_t)b * 128 + 96 + ch) << 16) + c;

    // Column-lifting pipeline state: e[j-1], e[j-2], o[j-1], dcol[j-2], dcol[j-3]
    float e1s = 0.f, e2s = 0.f, o1s = 0.f, dc1s = 0.f, dc2s = 0.f;
    float e1d = 0.f, e2d = 0.f, o1d = 0.f, dc1d = 0.f, dc2d = 0.f;

    const int js = (seg == 0) ? 0 : (j0 - 2);   // always even -> parity 0
    const int je = j0 + JSEG + 1;               // inclusive; 257 for last segment

    const bool mainPath = (c >= 2) && (c <= 253);
    const bool firstSeg = (seg == 0);

    // prologue: stage row pair js (one 16B/lane async copy covers both rows)
    g2lds16(ib + (size_t)(2 * js) * W + tid * 4, &buf[0][tid * 4]);
    __syncthreads();   // vmcnt(0) drain inside -> buf[0] ready

    for (int j = js; j <= je; ++j) {
        const int cur = j & 1;

        // prefetch next row pair into the other buffer (overlaps with compute)
        if (j < je && (j + 1) <= HP - 1)
            g2lds16(ib + (size_t)(2 * (j + 1)) * W + tid * 4, &buf[cur ^ 1][tid * 4]);

        float es, ed, os, od;
        if (j <= HP - 1) {
            const float* p0 = &buf[cur][0];
            row_lift(p0,     c, mainPath, es, ed);   // even row 2j
            row_lift(p0 + W, c, mainPath, os, od);   // odd row 2j+1
        } else {
            es = e2s; ed = e2d;                      // e[256] -> e[254]
            os = 0.f; od = 0.f;
        }

        // dcol[j-1] = o[j-1] - 0.5*(e[j-2] + e[j])   (e[-1]->e[1] at j==1,seg0)
        float dnew_s, dnew_d;
        if (j == 257) {                              // dcol[256] -> dcol[254]
            dnew_s = dc2s; dnew_d = dc2d;
        } else {
            float e2s_eff = (firstSeg && j == 1) ? es : e2s;
            float e2d_eff = (firstSeg && j == 1) ? ed : e2d;
            dnew_s = o1s - 0.5f * (e2s_eff + es);
            dnew_d = o1d - 0.5f * (e2d_eff + ed);
        }

        const int rD = j - 1;
        if (rD >= j0 && rD < j0 + JSEG) {
            __builtin_nontemporal_store(dnew_s, &outLH[rD * WP]);
            __builtin_nontemporal_store(dnew_d, &outHH[rD * WP]);
        }

        // scol[j-2] = e[j-2] + 0.25*(dcol[j-3] + dcol[j-1])  (dcol[-1]->dcol[1])
        float dc2s_eff = (firstSeg && j == 2) ? dnew_s : dc2s;
        float dc2d_eff = (firstSeg && j == 2) ? dnew_d : dc2d;
        float snew_s = e2s + 0.25f * (dc2s_eff + dnew_s);
        float snew_d = e2d + 0.25f * (dc2d_eff + dnew_d);

        const int rS = j - 2;
        if (rS >= j0 && rS < j0 + JSEG) {
            __builtin_nontemporal_store(snew_s, &outLL[rS * WP]);
            __builtin_nontemporal_store(snew_d, &outHL[rS * WP]);
        }

        // shift pipeline
        dc2s = dc1s; dc1s = dnew_s; e2s = e1s; e1s = es; o1s = os;
        dc2d = dc1d; dc1d = dnew_d; e2d = e1d; e1d = ed; o1d = od;

        __syncthreads();   // drains prefetch (vmcnt) + protects buffer reuse
    }
}

extern "C" void kernel_launch(void* const* d_in, const int* in_sizes, int n_in,
                              void* d_out, int out_size, void* d_ws, size_t ws_size,
                              hipStream_t stream) {
    const float* x = (const float*)d_in[0];
    float* out = (float*)d_out;
    dim3 grid(IMGS * SEGS);   // 2048 blocks
    dim3 block(256);
    hipLaunchKernelGGL(lwt53_2d_fused, grid, block, 0, stream, x, out);
}

// Round 2
// 460.227 us; speedup vs baseline: 1.1132x; 1.0038x over previous
//
#include <hip/hip_runtime.h>

#define H    512
#define W    512
#define HP   256   // row pairs (output height per quadrant)
#define WP   256   // output columns per quadrant
#define JSEG 16    // row-pairs per segment (16 -> 4096 blocks)
#define SEGS (HP / JSEG)   // 16
#define IMGS 256   // 8*32

typedef __attribute__((ext_vector_type(2))) float f32x2;

// Row lifting for a column pair (c0=2t, c1=2t+1) from 3 contiguous float4
// chunks [p[4t-4..4t+7]].  Edge columns handled by clamped chunks + 2 selects:
//   t==0  : Lm1 = chunk0 dup  -> d[c0] formula is automatically right;
//           dm (=d[-1]) reflects to d[1] = d1v.
//   t==127: Lp1 = chunk127 dup -> d[c1] formula is automatically right;
//           dp (=d[256]) reflects to d[254] = d0v.
__device__ __forceinline__ void rowlift2(float4 Lm1, float4 L0, float4 Lp1,
                                         bool edgeL, bool edgeR,
                                         float& s0, float& d0, float& s1, float& d1)
{
    float dmv = Lm1.w - 0.5f * (Lm1.x + L0.x);   // d[c0-1]
    float d0v = L0.y  - 0.5f * (Lm1.z + L0.z);   // d[c0]
    float d1v = L0.w  - 0.5f * (L0.x  + Lp1.x);  // d[c1]
    float dpv = Lp1.y - 0.5f * (L0.z  + Lp1.z);  // d[c1+1]
    if (edgeL) dmv = d1v;
    if (edgeR) dpv = d0v;
    s0 = L0.x + 0.25f * (dmv + d1v);
    s1 = L0.z + 0.25f * (d0v + dpv);
    d0 = d0v; d1 = d1v;
}

// One column-lifting step for one stream (state in registers, shifts inlined).
__device__ __forceinline__ void colstep(float e_in, float o_in,
    float& e1, float& e2, float& o1, float& dc1, float& dc2,
    bool firstSeg, int j, float& dnew, float& snew)
{
    if (j == 257) {                       // dcol[256] -> dcol[254]
        dnew = dc2;
    } else {
        float e2e = (firstSeg && j == 1) ? e_in : e2;   // e[-1] -> e[1]
        dnew = o1 - 0.5f * (e2e + e_in);
    }
    float dc2e = (firstSeg && j == 2) ? dnew : dc2;     // dcol[-1] -> dcol[1]
    snew = e2 + 0.25f * (dc2e + dnew);
    dc2 = dc1; dc1 = dnew; e2 = e1; e1 = e_in; o1 = o_in;
}

__global__ __launch_bounds__(128, 4)
void lwt53_2d_fused(const float* __restrict__ x, float* __restrict__ out)
{
    const int t   = threadIdx.x;            // column pair 0..127
    const int img = blockIdx.x / SEGS;      // 0..255 (= b*32 + ch)
    const int seg = blockIdx.x % SEGS;
    const int j0  = seg * JSEG;

    const float* ib = x + (size_t)img * (H * W);
    const int b  = img >> 5;
    const int ch = img & 31;
    const int col = 2 * t;
    // out[((b*128 + q*32 + ch)*256 + row)*256 + col], q: 0=LL 1=LH 2=HL 3=HH
    float* const outLL = out + (((size_t)b * 128 +  0 + ch) << 16) + col;
    float* const outLH = out + (((size_t)b * 128 + 32 + ch) << 16) + col;
    float* const outHL = out + (((size_t)b * 128 + 64 + ch) << 16) + col;
    float* const outHH = out + (((size_t)b * 128 + 96 + ch) << 16) + col;

    const int om1 = 4 * (t == 0   ? 0   : t - 1);   // clamped chunk offsets (floats)
    const int o0  = 4 * t;
    const int op1 = 4 * (t == 127 ? 127 : t + 1);
    const bool edgeL = (t == 0);
    const bool edgeR = (t == 127);

    // 4 column pipelines: {s,d} streams x {col0, col1}
    float e1s0=0,e2s0=0,o1s0=0,dc1s0=0,dc2s0=0;
    float e1d0=0,e2d0=0,o1d0=0,dc1d0=0,dc2d0=0;
    float e1s1=0,e2s1=0,o1s1=0,dc1s1=0,dc2s1=0;
    float e1d1=0,e2d1=0,o1d1=0,dc1d1=0,dc2d1=0;

    const int js = (seg == 0) ? 0 : (j0 - 2);       // always even
    const int je = j0 + JSEG + 1;                   // inclusive; 257 on last seg
    const bool firstSeg = (seg == 0);
    const int jload_max = (je < HP - 1) ? je : (HP - 1);

    float4 AE0,AE1,AE2, AO0,AO1,AO2;                // double-buffered row pair
    float4 BE0,BE1,BE2, BO0,BO1,BO2;

#define LOADPAIR(JN, E0,E1,E2,O0,O1,O2) do {                       \
        int jn_ = (JN);                                            \
        if (jn_ <= jload_max) {                                    \
            const float* rb_ = ib + (size_t)(2 * jn_) * W;         \
            E0 = *(const float4*)(rb_ + om1);                      \
            E1 = *(const float4*)(rb_ + o0);                       \
            E2 = *(const float4*)(rb_ + op1);                      \
            O0 = *(const float4*)(rb_ + W + om1);                  \
            O1 = *(const float4*)(rb_ + W + o0);                   \
            O2 = *(const float4*)(rb_ + W + op1);                  \
        }                                                          \
    } while (0)

#define BODY(J, E0,E1,E2,O0,O1,O2) do {                                        \
        const int j_ = (J);                                                    \
        float es0,ed0,es1,ed1, os0,od0,os1,od1;                                \
        if (j_ <= HP - 1) {                                                    \
            rowlift2(E0,E1,E2, edgeL, edgeR, es0, ed0, es1, ed1);              \
            rowlift2(O0,O1,O2, edgeL, edgeR, os0, od0, os1, od1);              \
        } else {                                                               \
            es0 = e2s0; ed0 = e2d0; es1 = e2s1; ed1 = e2d1;   /* e[256]->e[254] */ \
            os0 = od0 = os1 = od1 = 0.f;                                       \
        }                                                                      \
        float dns0,sns0, dnd0,snd0, dns1,sns1, dnd1,snd1;                      \
        colstep(es0, os0, e1s0,e2s0,o1s0,dc1s0,dc2s0, firstSeg, j_, dns0, sns0); \
        colstep(ed0, od0, e1d0,e2d0,o1d0,dc1d0,dc2d0, firstSeg, j_, dnd0, snd0); \
        colstep(es1, os1, e1s1,e2s1,o1s1,dc1s1,dc2s1, firstSeg, j_, dns1, sns1); \
        colstep(ed1, od1, e1d1,e2d1,o1d1,dc1d1,dc2d1, firstSeg, j_, dnd1, snd1); \
        const int rD_ = j_ - 1;                                                \
        if (rD_ >= j0 && rD_ < j0 + JSEG) {                                    \
            f32x2 vLH = {dns0, dns1}; f32x2 vHH = {dnd0, dnd1};                \
            __builtin_nontemporal_store(vLH, (f32x2*)(outLH + (size_t)rD_ * WP)); \
            __builtin_nontemporal_store(vHH, (f32x2*)(outHH + (size_t)rD_ * WP)); \
        }                                                                      \
        const int rS_ = j_ - 2;                                                \
        if (rS_ >= j0 && rS_ < j0 + JSEG) {                                    \
            f32x2 vLL = {sns0, sns1}; f32x2 vHL = {snd0, snd1};                \
            __builtin_nontemporal_store(vLL, (f32x2*)(outLL + (size_t)rS_ * WP)); \
            __builtin_nontemporal_store(vHL, (f32x2*)(outHL + (size_t)rS_ * WP)); \
        }                                                                      \
    } while (0)

    // prologue: pair js into set A; loop consumes A/B alternately with
    // distance-1 register prefetch (trip count is always even: 18 or 20).
    LOADPAIR(js, AE0,AE1,AE2,AO0,AO1,AO2);
    for (int j = js; j <= je; j += 2) {
        LOADPAIR(j + 1, BE0,BE1,BE2,BO0,BO1,BO2);
        BODY(j, AE0,AE1,AE2,AO0,AO1,AO2);
        LOADPAIR(j + 2, AE0,AE1,AE2,AO0,AO1,AO2);
        BODY(j + 1, BE0,BE1,BE2,BO0,BO1,BO2);
    }

#undef LOADPAIR
#undef BODY
}

extern "C" void kernel_launch(void* const* d_in, const int* in_sizes, int n_in,
                              void* d_out, int out_size, void* d_ws, size_t ws_size,
                              hipStream_t stream) {
    const float* x = (const float*)d_in[0];
    float* out = (float*)d_out;
    dim3 grid(IMGS * SEGS);   // 4096 blocks
    dim3 block(128);
    hipLaunchKernelGGL(lwt53_2d_fused, grid, block, 0, stream, x, out);
}